// Round 6
// baseline (762.046 us; speedup 1.0000x reference)
//
#include <hip/hip_runtime.h>
#include <math.h>

// Problem constants (from reference)
#define BATCH 16384
#define PP    208      // ids per row (26 features * 8 slots)
#define NF    26       // feature categories
#define VPF   50000u   // vocab per feature
#define EMB   32       // embed dim
#define DD    832      // NF * EMB
#define VOCAB (NF * 50000)

// ---------------------------------------------------------------------------
// Fully fused: embedding gather + per-category segment-sum + MLP + sigmoid.
// One batch row per block, 16384 blocks x 256 threads.
//
// Phase 1 (gather, R2/R5-proven structure): 8 chunks x 32 embed dims;
//   chunk (tid>>5) handles 26 of the 208 ids; lane e = tid&31 owns dim e.
//   atomicAdd into s_pool[cat*32+e] (bank == e -> conflict-free, collisions
//   only across chunks). 2-deep explicit load batches.
// Phase 2 (h0 = relu(pool @ W0 + b0)): wave s (of 4) = k-split s; thread
//   (s, c=tid&63) accumulates sum_{k in 208-chunk} s_pool[k] * W0[k][c].
//   s_pool reads are wave-uniform (broadcast); W0 reads are 256B coalesced
//   and L2-resident (213 KB total, every block reads the same).
// Phase 3: h1 = relu(h0 @ W1 + b1)  (16 threads x 64 MACs)
// Phase 4: z = h1 @ W2 -> sigmoid -> out[row]
//
// All f32 math -> bit-accurate vs reference (absmax ~1e-6).
// MLP phases add ~11 us aggregate VALU, hidden under the gather's memory
// stall (VALUBusy was 4%).
// ---------------------------------------------------------------------------
__global__ __launch_bounds__(256, 4) void fused_kernel(const int* __restrict__ x,
                                                       const float* __restrict__ table,
                                                       const float* __restrict__ W0,
                                                       const float* __restrict__ b0,
                                                       const float* __restrict__ W1,
                                                       const float* __restrict__ b1,
                                                       const float* __restrict__ W2,
                                                       float* __restrict__ out) {
    __shared__ int   s_ids[PP];
    __shared__ float s_pool[DD];
    __shared__ float s_part[4][64];
    __shared__ float sH[64];
    __shared__ float sH1[16];

    const int    tid = threadIdx.x;
    const size_t row = blockIdx.x;

    // ---- Phase 1: gather + segment-sum ----
    for (int i = tid; i < DD; i += 256) s_pool[i] = 0.0f;
    if (tid < PP / 4)
        reinterpret_cast<int4*>(s_ids)[tid] =
            reinterpret_cast<const int4*>(x + row * PP)[tid];
    __syncthreads();

    {
        const int e  = tid & 31;
        const int p0 = (tid >> 5) * 26;
        float* pool  = s_pool + e;

#pragma unroll 1
        for (int b = 0; b < 26; b += 2) {
            const unsigned id0 = (unsigned)s_ids[p0 + b + 0];
            const unsigned id1 = (unsigned)s_ids[p0 + b + 1];
            const float v0 = table[(size_t)id0 * EMB + e];
            const float v1 = table[(size_t)id1 * EMB + e];
            atomicAdd(pool + (id0 / VPF) * EMB, v0);
            atomicAdd(pool + (id1 / VPF) * EMB, v1);
        }
    }
    __syncthreads();

    // ---- Phase 2: h0 partials (4-way k-split over waves) ----
    {
        const int c = tid & 63;        // output column
        const int s = tid >> 6;        // k-split == wave id
        const int k0 = s * 208;
        const float* w = W0 + (size_t)k0 * 64 + c;
        float acc = 0.0f;
#pragma unroll 8
        for (int kk = 0; kk < 208; ++kk)
            acc = fmaf(s_pool[k0 + kk], w[(size_t)kk * 64], acc);
        s_part[s][c] = acc;
    }
    __syncthreads();

    // ---- Phase 3a: combine + bias + relu ----
    if (tid < 64) {
        const float h = s_part[0][tid] + s_part[1][tid] + s_part[2][tid] +
                        s_part[3][tid] + b0[tid];
        sH[tid] = fmaxf(h, 0.0f);
    }
    __syncthreads();

    // ---- Phase 3b: h1 = relu(h0 @ W1 + b1) ----
    if (tid < 16) {
        float a = b1[tid];
#pragma unroll 8
        for (int k = 0; k < 64; ++k)
            a = fmaf(sH[k], W1[k * 16 + tid], a);
        sH1[tid] = fmaxf(a, 0.0f);
    }
    __syncthreads();

    // ---- Phase 4: logit + sigmoid ----
    if (tid == 0) {
        float z = 0.0f;
#pragma unroll
        for (int j = 0; j < 16; ++j) z = fmaf(sH1[j], W2[j], z);
        out[row] = 1.0f / (1.0f + expf(-z));
    }
}

extern "C" void kernel_launch(void* const* d_in, const int* in_sizes, int n_in,
                              void* d_out, int out_size, void* d_ws, size_t ws_size,
                              hipStream_t stream) {
    const int*   x     = (const int*)d_in[0];
    const float* table = (const float*)d_in[1];
    const float* W0    = (const float*)d_in[2];
    const float* b0    = (const float*)d_in[3];
    const float* W1    = (const float*)d_in[4];
    const float* b1    = (const float*)d_in[5];
    const float* W2    = (const float*)d_in[6];
    float*       out   = (float*)d_out;

    fused_kernel<<<BATCH, 256, 0, stream>>>(x, table, W0, b0, W1, b1, W2, out);
}